// Round 11
// baseline (474.171 us; speedup 1.0000x reference)
//
#include <hip/hip_runtime.h>
#include <cmath>

#define NNODES 32768
#define NEDGES 524288
#define NBATCH 16
#define NSAMP  2048
#define EPS    1e-5f

#define PK2 72    // 64 + 8 pad (shorts); row stride 144 B (16B-multiple)

typedef short s16x8 __attribute__((ext_vector_type(8)));
typedef float f32x4 __attribute__((ext_vector_type(4)));
typedef unsigned short ushort_t;

struct YArr { float v[192]; };

static __device__ __forceinline__ unsigned short f2bf(float f) {
  unsigned int u = __float_as_uint(f);
  u = (u + 0x7fffu + ((u >> 16) & 1u)) >> 16;   // RN-even
  return (unsigned short)u;
}
static __device__ __forceinline__ float bf2f(unsigned short b) {
  return __uint_as_float(((unsigned int)b) << 16);
}

// ------------- setup: weight prep (blocks 0..383) + CSR count (blocks 384..2431) ----
__global__ __launch_bounds__(256) void setup_kernel(
    const float* __restrict__ m1W, const float* __restrict__ m2W,
    const float* __restrict__ u1W, const float* __restrict__ u2W,
    ushort_t* __restrict__ wc_hi, ushort_t* __restrict__ wc_lo,
    ushort_t* __restrict__ w1b_hi, ushort_t* __restrict__ w1b_lo,
    ushort_t* __restrict__ w2e_hi, ushort_t* __restrict__ w2e_lo,
    ushort_t* __restrict__ w2n_hi, ushort_t* __restrict__ w2n_lo,
    const int* __restrict__ edst, int* __restrict__ cnt)
{
  if (blockIdx.x >= 384) {
    int e = (blockIdx.x - 384) * 256 + threadIdx.x;
    if (e < NEDGES) atomicAdd(&cnt[edst[e]], 1);
    return;
  }
  int t = blockIdx.x * 256 + threadIdx.x;
  if (t >= 4 * 24576) return;
  int l = t / 24576;
  int r = t % 24576;
  float w; ushort_t *dh, *dl;
  if (r < 12288) {                      // Wcomb: P|Q|R
    int j = r >> 6, k = r & 63;
    if (j < 64)       w = m1W[l*8192 + k*64 + j];
    else if (j < 128) w = m1W[l*8192 + (64 + k)*64 + (j - 64)];
    else              w = u1W[l*8192 + k*64 + (j - 128)];
    int off = l*192*PK2 + j*PK2 + k;
    dh = wc_hi + off; dl = wc_lo + off;
  } else if (r < 16384) {               // W1b
    int idx = r - 12288;
    int j = idx & 63, k = idx >> 6;
    w = u1W[l*8192 + (64 + k)*64 + j];
    int off = l*64*PK2 + j*PK2 + k;
    dh = w1b_hi + off; dl = w1b_lo + off;
  } else if (r < 20480) {               // W2e
    int idx = r - 16384;
    int j = idx & 63, k = idx >> 6;
    w = m2W[l*4096 + k*64 + j];
    int off = l*64*PK2 + j*PK2 + k;
    dh = w2e_hi + off; dl = w2e_lo + off;
  } else {                              // W2n
    int idx = r - 20480;
    int j = idx & 63, k = idx >> 6;
    w = u2W[l*4096 + k*64 + j];
    int off = l*64*PK2 + j*PK2 + k;
    dh = w2n_hi + off; dl = w2n_lo + off;
  }
  unsigned short hb = f2bf(w);
  *dh = hb;
  *dl = f2bf(w - bf2f(hb));
}

__global__ __launch_bounds__(1024) void scan_kernel(const int* __restrict__ cnt,
                                                    int* __restrict__ offs,
                                                    int* __restrict__ cursor) {
  __shared__ int sc[1024];
  int tid = threadIdx.x;
  int base = tid * 32;
  int s = 0;
  #pragma unroll
  for (int i = 0; i < 32; i++) s += cnt[base + i];
  sc[tid] = s; __syncthreads();
  int own = s;
  for (int off = 1; off < 1024; off <<= 1) {
    int v = (tid >= off) ? sc[tid - off] : 0;
    __syncthreads();
    sc[tid] += v;
    __syncthreads();
  }
  int run = sc[tid] - own;
  for (int i = 0; i < 32; i++) {
    offs[base + i] = run; cursor[base + i] = run;
    run += cnt[base + i];
  }
}

__global__ __launch_bounds__(256) void fill_kernel(
    const int* __restrict__ esrc, const int* __restrict__ edst,
    int* __restrict__ cursor, int* __restrict__ psrc, int* __restrict__ pdst) {
  int e = blockIdx.x * 256 + threadIdx.x;
  if (e < NEDGES) {
    int d = edst[e];
    int pos = atomicAdd(&cursor[d], 1);
    psrc[pos] = esrc[e];
    pdst[pos] = d;
  }
}

// ------------- fused (encode|norm) + P|Q|R GEMM -------------
template<int MODE>
__global__ __launch_bounds__(256) void norm_pqr_kernel(
    const float* __restrict__ in,     // x (MODE 0) or u (MODE 1)
    const float* __restrict__ sA, const float* __restrict__ sB,
    const float* __restrict__ encW, const float* __restrict__ encb,
    const ushort_t* __restrict__ Wh, const ushort_t* __restrict__ Wl,
    float* __restrict__ P, float* __restrict__ Q, float* __restrict__ Rb)
{
  __shared__ __align__(16) ushort_t sAh[4][16*PK2];
  __shared__ __align__(16) ushort_t sAl[4][16*PK2];
  int tid = threadIdx.x, lane = tid & 63, wave = tid >> 6;
  int l15 = lane & 15, quad = lane >> 4;
  int base = blockIdx.x * 64 + wave * 16;
  int g = blockIdx.x >> 5;

  float mean = 0.f, rstd = 1.f, w0 = 0.f, w1 = 0.f, w2 = 0.f, bb = 0.f;
  if (MODE) {
    float a = sA[g*64 + lane], q = sB[g*64 + lane];
    mean = a * (1.f / NSAMP);
    float var = q * (1.f / NSAMP) - mean * mean;
    rstd = rsqrtf(var + EPS);
  } else {
    w0 = encW[lane]; w1 = encW[64 + lane]; w2 = encW[128 + lane];
    bb = encb[lane];
  }

  ushort_t* ah_s = sAh[wave];
  ushort_t* al_s = sAl[wave];
  #pragma unroll
  for (int r = 0; r < 16; r++) {
    int n = base + r;
    float v;
    if (MODE) v = (in[(size_t)n*64 + lane] - mean) * rstd;
    else      v = fmaf(in[n*3+2], w2, fmaf(in[n*3+1], w1, fmaf(in[n*3+0], w0, bb)));
    unsigned short hb = f2bf(v);
    ah_s[r*PK2 + lane] = hb;
    al_s[r*PK2 + lane] = f2bf(v - bf2f(hb));
  }

  s16x8 ah[2], al[2];
  #pragma unroll
  for (int kb = 0; kb < 2; kb++) {
    int idx = l15*PK2 + kb*32 + quad*8;
    ah[kb] = *(const s16x8*)&ah_s[idx];
    al[kb] = *(const s16x8*)&al_s[idx];
  }

  #pragma unroll
  for (int ct = 0; ct < 12; ct++) {
    f32x4 acc = (f32x4){0.f, 0.f, 0.f, 0.f};
    #pragma unroll
    for (int kb = 0; kb < 2; kb++) {
      int woff = (ct*16 + l15)*PK2 + kb*32 + quad*8;
      s16x8 bh = *(const s16x8*)(Wh + woff);
      s16x8 bl = *(const s16x8*)(Wl + woff);
      acc = __builtin_amdgcn_mfma_f32_16x16x32_bf16(al[kb], bl, acc, 0, 0, 0);
      acc = __builtin_amdgcn_mfma_f32_16x16x32_bf16(al[kb], bh, acc, 0, 0, 0);
      acc = __builtin_amdgcn_mfma_f32_16x16x32_bf16(ah[kb], bl, acc, 0, 0, 0);
      acc = __builtin_amdgcn_mfma_f32_16x16x32_bf16(ah[kb], bh, acc, 0, 0, 0);
    }
    int j = ct*16 + l15;
    float* dst; int jj;
    if (ct < 4)      { dst = P;  jj = j; }
    else if (ct < 8) { dst = Q;  jj = j - 64; }
    else             { dst = Rb; jj = j - 128; }
    #pragma unroll
    for (int rr = 0; rr < 4; rr++) {
      int row = base + quad*4 + rr;
      dst[(size_t)row*64 + jj] = acc[rr];
    }
  }
}

// ------------- fused edge MLP + segment-reduce (R9 body, grid 1024) --------
__global__ __launch_bounds__(256, 3) void edge_fused_kernel(
    const float* __restrict__ Pbuf, const float* __restrict__ Qbuf,
    const int* __restrict__ psrc, const int* __restrict__ pdst,
    const float* __restrict__ b1,
    const ushort_t* __restrict__ W2hi, const ushort_t* __restrict__ W2lo,
    const float* __restrict__ b2,
    float* __restrict__ agg)
{
  __shared__ __align__(16) char smem[4][9216];
  __shared__ int  sSD[4][64];

  int tid = threadIdx.x;
  int lane = tid & 63, wave = tid >> 6;
  int l15 = lane & 15, quad = lane >> 4;

  ushort_t* mh = (ushort_t*)smem[wave];
  ushort_t* ml = mh + 32*PK2;
  float*    m2 = (float*)smem[wave];

  s16x8 w2h[2][4], w2l[2][4];
  #pragma unroll
  for (int kb = 0; kb < 2; kb++)
    #pragma unroll
    for (int ct = 0; ct < 4; ct++) {
      int off = (ct*16 + l15)*PK2 + kb*32 + quad*8;
      w2h[kb][ct] = *(const s16x8*)(W2hi + off);
      w2l[kb][ct] = *(const s16x8*)(W2lo + off);
    }
  float b1v = b1[lane];
  float b2v[4];
  #pragma unroll
  for (int ct = 0; ct < 4; ct++) b2v[ct] = b2[ct*16 + l15];

  for (int base = blockIdx.x * 128; base < NEDGES; base += gridDim.x * 128) {
    int e0 = base + wave * 32;

    {
      const int* tb = (lane < 32) ? psrc : pdst;
      int i = (lane < 32) ? (e0 + lane) : (e0 + lane - 32);
      sSD[wave][lane] = tb[i];
    }

    #pragma unroll
    for (int rb = 0; rb < 4; rb++) {
      float pv[8], qv[8];
      #pragma unroll
      for (int i = 0; i < 8; i++) {
        int r = rb*8 + i;
        int s = sSD[wave][r];
        int d = sSD[wave][32 + r];
        qv[i] = Qbuf[((size_t)s << 6) + lane];
        pv[i] = Pbuf[((size_t)d << 6) + lane];
      }
      #pragma unroll
      for (int i = 0; i < 8; i++) {
        int r = rb*8 + i;
        float v = fmaxf(pv[i] + qv[i] + b1v, 0.f);
        unsigned short hb = f2bf(v);
        mh[r*PK2 + lane] = hb;
        ml[r*PK2 + lane] = f2bf(v - bf2f(hb));
      }
    }

    f32x4 facc[2][4];
    #pragma unroll
    for (int rt = 0; rt < 2; rt++)
      #pragma unroll
      for (int ct = 0; ct < 4; ct++)
        facc[rt][ct] = (f32x4){0.f, 0.f, 0.f, 0.f};

    #pragma unroll
    for (int kb = 0; kb < 2; kb++) {
      s16x8 mhf[2], mlf[2];
      #pragma unroll
      for (int rt = 0; rt < 2; rt++) {
        int idx = (rt*16 + l15)*PK2 + kb*32 + quad*8;
        mhf[rt] = *(const s16x8*)&mh[idx];
        mlf[rt] = *(const s16x8*)&ml[idx];
      }
      #pragma unroll
      for (int ct = 0; ct < 4; ct++)
        #pragma unroll
        for (int rt = 0; rt < 2; rt++) {
          facc[rt][ct] = __builtin_amdgcn_mfma_f32_16x16x32_bf16(mlf[rt], w2l[kb][ct], facc[rt][ct], 0, 0, 0);
          facc[rt][ct] = __builtin_amdgcn_mfma_f32_16x16x32_bf16(mlf[rt], w2h[kb][ct], facc[rt][ct], 0, 0, 0);
          facc[rt][ct] = __builtin_amdgcn_mfma_f32_16x16x32_bf16(mhf[rt], w2l[kb][ct], facc[rt][ct], 0, 0, 0);
          facc[rt][ct] = __builtin_amdgcn_mfma_f32_16x16x32_bf16(mhf[rt], w2h[kb][ct], facc[rt][ct], 0, 0, 0);
        }
    }

    #pragma unroll
    for (int rt = 0; rt < 2; rt++)
      #pragma unroll
      for (int ct = 0; ct < 4; ct++)
        #pragma unroll
        for (int r = 0; r < 4; r++)
          m2[(rt*16 + quad*4 + r)*68 + ct*16 + l15] = fmaxf(facc[rt][ct][r] + b2v[ct], 0.f);

    int curd = sSD[wave][32];
    float acc = 0.f;
    #pragma unroll
    for (int r = 0; r < 32; r++) {
      int d = sSD[wave][32 + r];
      float v = m2[r*68 + lane];
      if (d != curd) {
        unsafeAtomicAdd(&agg[((size_t)curd << 6) + lane], acc);
        acc = 0.f; curd = d;
      }
      acc += v;
    }
    unsafeAtomicAdd(&agg[((size_t)curd << 6) + lane], acc);
  }
}

// ------------- node MLP -------------
__global__ __launch_bounds__(256) void node_mfma_kernel(
    const float* __restrict__ aggF, const float* __restrict__ Rbuf,
    const ushort_t* __restrict__ W1h, const ushort_t* __restrict__ W1l,
    const float* __restrict__ b1,
    const ushort_t* __restrict__ W2h, const ushort_t* __restrict__ W2l,
    const float* __restrict__ b2,
    float* __restrict__ uout, float* __restrict__ sA, float* __restrict__ sB)
{
  __shared__ __align__(16) ushort_t sMh[4][16*PK2];
  __shared__ __align__(16) ushort_t sMl[4][16*PK2];
  int tid = threadIdx.x, lane = tid & 63, wave = tid >> 6;
  int l15 = lane & 15, quad = lane >> 4;
  int base = blockIdx.x * 64 + wave * 16;
  int g = blockIdx.x >> 5;

  s16x8 ah[2], al[2];
  {
    int em = base + l15;
    #pragma unroll
    for (int kb = 0; kb < 2; kb++) {
      size_t off = (size_t)em*64 + kb*32 + quad*8;
      float4 v0 = *(const float4*)(aggF + off);
      float4 v1 = *(const float4*)(aggF + off + 4);
      float vv[8] = {v0.x,v0.y,v0.z,v0.w,v1.x,v1.y,v1.z,v1.w};
      s16x8 hh, ll;
      #pragma unroll
      for (int j = 0; j < 8; j++) {
        unsigned short hb = f2bf(vv[j]);
        hh[j] = (short)hb;
        ll[j] = (short)f2bf(vv[j] - bf2f(hb));
      }
      ah[kb] = hh; al[kb] = ll;
    }
  }

  ushort_t* mh = sMh[wave];
  ushort_t* ml = sMl[wave];
  float b1v[4], b2v[4];
  #pragma unroll
  for (int ct = 0; ct < 4; ct++) { b1v[ct] = b1[ct*16+l15]; b2v[ct] = b2[ct*16+l15]; }

  #pragma unroll
  for (int ct = 0; ct < 4; ct++) {
    f32x4 acc = (f32x4){0.f, 0.f, 0.f, 0.f};
    #pragma unroll
    for (int kb = 0; kb < 2; kb++) {
      int woff = (ct*16 + l15)*PK2 + kb*32 + quad*8;
      s16x8 bh = *(const s16x8*)(W1h + woff);
      s16x8 bl = *(const s16x8*)(W1l + woff);
      acc = __builtin_amdgcn_mfma_f32_16x16x32_bf16(al[kb], bl, acc, 0, 0, 0);
      acc = __builtin_amdgcn_mfma_f32_16x16x32_bf16(al[kb], bh, acc, 0, 0, 0);
      acc = __builtin_amdgcn_mfma_f32_16x16x32_bf16(ah[kb], bl, acc, 0, 0, 0);
      acc = __builtin_amdgcn_mfma_f32_16x16x32_bf16(ah[kb], bh, acc, 0, 0, 0);
    }
    int j = ct*16 + l15;
    #pragma unroll
    for (int rr = 0; rr < 4; rr++) {
      int row = quad*4 + rr;
      float v = acc[rr] + Rbuf[(size_t)(base+row)*64 + j] + b1v[ct];
      v = fmaxf(v, 0.f);
      unsigned short hb = f2bf(v);
      mh[row*PK2 + j] = hb;
      ml[row*PK2 + j] = f2bf(v - bf2f(hb));
    }
  }

  s16x8 mhf[2], mlf[2];
  #pragma unroll
  for (int kb = 0; kb < 2; kb++) {
    int idx = l15*PK2 + kb*32 + quad*8;
    mhf[kb] = *(const s16x8*)&mh[idx];
    mlf[kb] = *(const s16x8*)&ml[idx];
  }
  #pragma unroll
  for (int ct = 0; ct < 4; ct++) {
    f32x4 facc = (f32x4){0.f, 0.f, 0.f, 0.f};
    #pragma unroll
    for (int kb = 0; kb < 2; kb++) {
      int woff = (ct*16 + l15)*PK2 + kb*32 + quad*8;
      s16x8 bh = *(const s16x8*)(W2h + woff);
      s16x8 bl = *(const s16x8*)(W2l + woff);
      facc = __builtin_amdgcn_mfma_f32_16x16x32_bf16(mlf[kb], bl, facc, 0, 0, 0);
      facc = __builtin_amdgcn_mfma_f32_16x16x32_bf16(mlf[kb], bh, facc, 0, 0, 0);
      facc = __builtin_amdgcn_mfma_f32_16x16x32_bf16(mhf[kb], bl, facc, 0, 0, 0);
      facc = __builtin_amdgcn_mfma_f32_16x16x32_bf16(mhf[kb], bh, facc, 0, 0, 0);
    }
    int j = ct*16 + l15;
    float s = 0.f, s2 = 0.f;
    #pragma unroll
    for (int rr = 0; rr < 4; rr++) {
      int row = quad*4 + rr;
      float v = fmaxf(facc[rr] + b2v[ct], 0.f);
      uout[(size_t)(base+row)*64 + j] = v;
      s += v; s2 += v*v;
    }
    s  += __shfl_xor(s, 16);  s  += __shfl_xor(s, 32);
    s2 += __shfl_xor(s2, 16); s2 += __shfl_xor(s2, 32);
    if (quad == 0) {
      unsafeAtomicAdd(&sA[g*64 + j], s);
      unsafeAtomicAdd(&sB[g*64 + j], s2);
    }
  }
}

// ------------- decoder -------------
__global__ __launch_bounds__(64) void decoder_kernel(
    const float* __restrict__ u, const float* __restrict__ sA,
    const float* __restrict__ sB, const float* __restrict__ W,
    const float* __restrict__ b, float* __restrict__ X)
{
  __shared__ float sh[64][65];
  __shared__ float sm[64], sr[64];
  int lane = threadIdx.x;
  int nb = blockIdx.x * 64;
  int g = blockIdx.x >> 5;
  {
    float a = sA[g*64 + lane], q = sB[g*64 + lane];
    float mean = a * (1.f / NSAMP);
    float var = q * (1.f / NSAMP) - mean * mean;
    sm[lane] = mean;
    sr[lane] = rsqrtf(var + EPS);
  }
  for (int r = 0; r < 64; r++) sh[r][lane] = u[(size_t)(nb + r) * 64 + lane];
  __syncthreads();
  float a0 = b[0], a1 = b[1], a2 = b[2];
  #pragma unroll
  for (int c = 0; c < 64; c++) {
    float v = (sh[lane][c] - sm[c]) * sr[c];
    a0 = fmaf(v, W[c*3+0], a0);
    a1 = fmaf(v, W[c*3+1], a1);
    a2 = fmaf(v, W[c*3+2], a2);
  }
  float inv = 1.f / sqrtf(a0*a0 + a1*a1 + a2*a2);
  int n = nb + lane;
  X[n*3+0] = a0 * inv;
  X[n*3+1] = a1 * inv;
  X[n*3+2] = a2 * inv;
}

// ------------- MMD: fused kXX (blocks 0..511) + kXY (blocks 512..527) ------
__device__ inline float block_reduce_sum(float v) {
  #pragma unroll
  for (int o = 32; o > 0; o >>= 1) v += __shfl_down(v, o, 64);
  __shared__ float red[4];
  int lane = threadIdx.x & 63, w = threadIdx.x >> 6;
  if (lane == 0) red[w] = v;
  __syncthreads();
  float t = 0.f;
  if (threadIdx.x == 0) t = red[0] + red[1] + red[2] + red[3];
  return t;
}

__global__ __launch_bounds__(256) void mmd_kernel(
    const float* __restrict__ X, YArr Y,
    float* __restrict__ kxx, float* __restrict__ kxy)
{
  if (blockIdx.x < 512) {
    int b  = blockIdx.x >> 5;
    int nt = blockIdx.x & 31;
    const float* Xb = X + (size_t)b * NSAMP * 3;
    __shared__ float sx[192];
    if (threadIdx.x < 192) sx[threadIdx.x] = Xb[nt*192 + threadIdx.x];
    __syncthreads();
    float ps = 0.f;
    for (int it = 0; it < 8; it++) {
      int m = it*256 + threadIdx.x;
      float x0 = Xb[m*3+0], x1 = Xb[m*3+1], x2 = Xb[m*3+2];
      #pragma unroll
      for (int n = 0; n < 64; n++) {
        float d = x0*sx[n*3+0] + x1*sx[n*3+1] + x2*sx[n*3+2];
        ps += __expf(2.f*d - 2.f);
      }
    }
    float t = block_reduce_sum(ps);
    if (threadIdx.x == 0) atomicAdd(&kxx[b], t);
  } else {
    int b = blockIdx.x - 512;
    const float* Xb = X + (size_t)b * NSAMP * 3;
    float ps = 0.f;
    for (int it = 0; it < 8; it++) {
      int n = it*256 + threadIdx.x;
      float x0 = Xb[n*3+0], x1 = Xb[n*3+1], x2 = Xb[n*3+2];
      #pragma unroll
      for (int m = 0; m < 64; m++) {
        float d = x0*Y.v[m*3+0] + x1*Y.v[m*3+1] + x2*Y.v[m*3+2];
        ps += __expf(2.f*d - 2.f);
      }
    }
    float t = block_reduce_sum(ps);
    if (threadIdx.x == 0) kxy[b] = t;
  }
}

__global__ void loss_kernel(const float* __restrict__ kxx,
                            const float* __restrict__ kxy,
                            float kyy, float* __restrict__ out)
{
  if (threadIdx.x == 0 && blockIdx.x == 0) {
    float s = 0.f;
    for (int b = 0; b < NBATCH; b++)
      s += kxx[b] * (1.0f/((float)NSAMP*(float)NSAMP))
         - 2.0f * kxy[b] * (1.0f/((float)NSAMP*64.0f));
    out[0] = s * (1.0f/NBATCH) + kyy;
  }
}

// ------------- launch -------------
extern "C" void kernel_launch(void* const* d_in, const int* in_sizes, int n_in,
                              void* d_out, int out_size, void* d_ws, size_t ws_size,
                              hipStream_t stream)
{
  const float* x    = (const float*)d_in[0];
  const int*   esrc = (const int*)  d_in[1];
  const int*   edst = (const int*)  d_in[2];
  const float* encW = (const float*)d_in[4];
  const float* encb = (const float*)d_in[5];
  const float* m1W  = (const float*)d_in[6];
  const float* m1b  = (const float*)d_in[7];
  const float* m2W  = (const float*)d_in[8];
  const float* m2b  = (const float*)d_in[9];
  const float* u1W  = (const float*)d_in[10];
  const float* u1b  = (const float*)d_in[11];
  const float* u2W  = (const float*)d_in[12];
  const float* u2b  = (const float*)d_in[13];
  const float* decW = (const float*)d_in[14];
  const float* decb = (const float*)d_in[15];
  float* out = (float*)d_out;

  const size_t NF = (size_t)NNODES * 64;
  // single zero region: [aggAll | statsA | statsB | kxx | icnt]
  float* aggAll = (float*)d_ws;        // 4 * NF
  float* statsA = aggAll + 4*NF;       // 4096
  float* statsB = statsA + 4096;       // 4096
  float* kxx    = statsB + 4096;       // 16
  int*   icnt   = (int*)(kxx + 16);    // 32768
  size_t zero_bytes = (4*NF + 4096 + 4096 + 16) * sizeof(float) + NNODES * sizeof(int);

  float* u_buf  = (float*)(icnt + NNODES);
  float* Pbuf   = u_buf + NF;
  float* Qbuf   = Pbuf + NF;
  float* Rbuf   = Qbuf + NF;
  float* kxy    = Rbuf + NF;           // 16
  int* ioffs    = (int*)(kxy + 16);
  int* icur     = ioffs + NNODES;
  int* psrc     = icur + NNODES;
  int* pdst     = psrc + NEDGES;
  ushort_t* us  = (ushort_t*)(pdst + NEDGES);
  ushort_t* wc_hi  = us;  us += 4*192*PK2;
  ushort_t* wc_lo  = us;  us += 4*192*PK2;
  ushort_t* w1b_hi = us;  us += 4*64*PK2;
  ushort_t* w1b_lo = us;  us += 4*64*PK2;
  ushort_t* w2e_hi = us;  us += 4*64*PK2;
  ushort_t* w2e_lo = us;  us += 4*64*PK2;
  ushort_t* w2n_hi = us;  us += 4*64*PK2;
  ushort_t* w2n_lo = us;  us += 4*64*PK2;

  float* X = out + 1;

  hipMemsetAsync(aggAll, 0, zero_bytes, stream);

  setup_kernel<<<384 + NEDGES/256, 256, 0, stream>>>(
      m1W, m2W, u1W, u2W,
      wc_hi, wc_lo, w1b_hi, w1b_lo, w2e_hi, w2e_lo, w2n_hi, w2n_lo,
      edst, icnt);
  scan_kernel<<<1, 1024, 0, stream>>>(icnt, ioffs, icur);
  fill_kernel<<<NEDGES/256, 256, 0, stream>>>(esrc, edst, icur, psrc, pdst);

  for (int l = 0; l < 4; l++) {
    const ushort_t* wch = wc_hi + (size_t)l*192*PK2;
    const ushort_t* wcl = wc_lo + (size_t)l*192*PK2;
    if (l == 0)
      norm_pqr_kernel<0><<<512, 256, 0, stream>>>(
          x, nullptr, nullptr, encW, encb, wch, wcl, Pbuf, Qbuf, Rbuf);
    else
      norm_pqr_kernel<1><<<512, 256, 0, stream>>>(
          u_buf, statsA + (l-1)*1024, statsB + (l-1)*1024, nullptr, nullptr,
          wch, wcl, Pbuf, Qbuf, Rbuf);

    edge_fused_kernel<<<1024, 256, 0, stream>>>(
        Pbuf, Qbuf, psrc, pdst, m1b + l*64,
        w2e_hi + (size_t)l*64*PK2, w2e_lo + (size_t)l*64*PK2, m2b + l*64,
        aggAll + (size_t)l*NF);

    node_mfma_kernel<<<512, 256, 0, stream>>>(
        aggAll + (size_t)l*NF, Rbuf,
        w1b_hi + (size_t)l*64*PK2, w1b_lo + (size_t)l*64*PK2, u1b + l*64,
        w2n_hi + (size_t)l*64*PK2, w2n_lo + (size_t)l*64*PK2, u2b + l*64,
        u_buf, statsA + l*1024, statsB + l*1024);
  }

  decoder_kernel<<<NNODES/64, 64, 0, stream>>>(
      u_buf, statsA + 3*1024, statsB + 3*1024, decW, decb, X);

  YArr Y;
  {
    const double pi = 3.14159265358979323846;
    double phi = pi * (3.0 - sqrt(5.0));
    for (int i = 0; i < 64; i++) {
      double y  = 1.0 - 2.0 * (double)i / 63.0;
      double r  = sqrt(fmax(0.0, 1.0 - y*y));
      double th = phi * (double)i;
      Y.v[i*3+0] = (float)(cos(th) * r);
      Y.v[i*3+1] = (float)y;
      Y.v[i*3+2] = (float)(sin(th) * r);
    }
  }
  double kyy_acc = 0.0;
  for (int i = 0; i < 64; i++)
    for (int j = 0; j < 64; j++) {
      double d = (double)Y.v[i*3+0]*Y.v[j*3+0]
               + (double)Y.v[i*3+1]*Y.v[j*3+1]
               + (double)Y.v[i*3+2]*Y.v[j*3+2];
      kyy_acc += exp(2.0*d - 2.0);
    }
  float kyy = (float)(kyy_acc / 4096.0);

  mmd_kernel<<<528, 256, 0, stream>>>(X, Y, kxx, kxy);
  loss_kernel<<<1, 64, 0, stream>>>(kxx, kxy, kyy, out);
}

// Round 12
// 438.349 us; speedup vs baseline: 1.0817x; 1.0817x over previous
//
#include <hip/hip_runtime.h>
#include <cmath>

#define NNODES 32768
#define NEDGES 524288
#define NBATCH 16
#define NSAMP  2048
#define EPS    1e-5f

#define PK2 72    // 64 + 8 pad (shorts); row stride 144 B (16B-multiple)

typedef short s16x8 __attribute__((ext_vector_type(8)));
typedef float f32x4 __attribute__((ext_vector_type(4)));
typedef unsigned short ushort_t;

struct YArr { float v[192]; };

static __device__ __forceinline__ unsigned short f2bf(float f) {
  unsigned int u = __float_as_uint(f);
  u = (u + 0x7fffu + ((u >> 16) & 1u)) >> 16;   // RN-even
  return (unsigned short)u;
}
static __device__ __forceinline__ float bf2f(unsigned short b) {
  return __uint_as_float(((unsigned int)b) << 16);
}

// ------------- setup: weight prep (blocks 0..383) + CSR count (blocks 384..) ----
__global__ __launch_bounds__(256) void setup_kernel(
    const float* __restrict__ m1W, const float* __restrict__ m2W,
    const float* __restrict__ u1W, const float* __restrict__ u2W,
    ushort_t* __restrict__ wc_hi, ushort_t* __restrict__ wc_lo,
    ushort_t* __restrict__ w1b_hi, ushort_t* __restrict__ w1b_lo,
    ushort_t* __restrict__ w2e_hi, ushort_t* __restrict__ w2e_lo,
    ushort_t* __restrict__ w2n_hi, ushort_t* __restrict__ w2n_lo,
    const int* __restrict__ edst, int* __restrict__ cnt)
{
  if (blockIdx.x >= 384) {
    int e = (blockIdx.x - 384) * 256 + threadIdx.x;
    if (e < NEDGES) atomicAdd(&cnt[edst[e]], 1);
    return;
  }
  int t = blockIdx.x * 256 + threadIdx.x;
  if (t >= 4 * 24576) return;
  int l = t / 24576;
  int r = t % 24576;
  float w; ushort_t *dh, *dl;
  if (r < 12288) {                      // Wcomb: P|Q|R
    int j = r >> 6, k = r & 63;
    if (j < 64)       w = m1W[l*8192 + k*64 + j];
    else if (j < 128) w = m1W[l*8192 + (64 + k)*64 + (j - 64)];
    else              w = u1W[l*8192 + k*64 + (j - 128)];
    int off = l*192*PK2 + j*PK2 + k;
    dh = wc_hi + off; dl = wc_lo + off;
  } else if (r < 16384) {               // W1b
    int idx = r - 12288;
    int j = idx & 63, k = idx >> 6;
    w = u1W[l*8192 + (64 + k)*64 + j];
    int off = l*64*PK2 + j*PK2 + k;
    dh = w1b_hi + off; dl = w1b_lo + off;
  } else if (r < 20480) {               // W2e
    int idx = r - 16384;
    int j = idx & 63, k = idx >> 6;
    w = m2W[l*4096 + k*64 + j];
    int off = l*64*PK2 + j*PK2 + k;
    dh = w2e_hi + off; dl = w2e_lo + off;
  } else {                              // W2n
    int idx = r - 20480;
    int j = idx & 63, k = idx >> 6;
    w = u2W[l*4096 + k*64 + j];
    int off = l*64*PK2 + j*PK2 + k;
    dh = w2n_hi + off; dl = w2n_lo + off;
  }
  unsigned short hb = f2bf(w);
  *dh = hb;
  *dl = f2bf(w - bf2f(hb));
}

__global__ __launch_bounds__(1024) void scan_kernel(const int* __restrict__ cnt,
                                                    int* __restrict__ offs,
                                                    int* __restrict__ cursor) {
  __shared__ int sc[1024];
  int tid = threadIdx.x;
  int base = tid * 32;
  int s = 0;
  #pragma unroll
  for (int i = 0; i < 32; i++) s += cnt[base + i];
  sc[tid] = s; __syncthreads();
  int own = s;
  for (int off = 1; off < 1024; off <<= 1) {
    int v = (tid >= off) ? sc[tid - off] : 0;
    __syncthreads();
    sc[tid] += v;
    __syncthreads();
  }
  int run = sc[tid] - own;
  for (int i = 0; i < 32; i++) {
    offs[base + i] = run; cursor[base + i] = run;
    run += cnt[base + i];
  }
}

__global__ __launch_bounds__(256) void fill_kernel(
    const int* __restrict__ esrc, const int* __restrict__ edst,
    int* __restrict__ cursor, int* __restrict__ psrc, int* __restrict__ pdst) {
  int e = blockIdx.x * 256 + threadIdx.x;
  if (e < NEDGES) {
    int d = edst[e];
    int pos = atomicAdd(&cursor[d], 1);
    psrc[pos] = esrc[e];
    pdst[pos] = d;
  }
}

// ------------- fused (encode|norm) + P|Q|R GEMM -------------
template<int MODE>
__global__ __launch_bounds__(256) void norm_pqr_kernel(
    const float* __restrict__ in,     // x (MODE 0) or u (MODE 1)
    const float* __restrict__ sA, const float* __restrict__ sB,
    const float* __restrict__ encW, const float* __restrict__ encb,
    const ushort_t* __restrict__ Wh, const ushort_t* __restrict__ Wl,
    float* __restrict__ P, float* __restrict__ Q, float* __restrict__ Rb)
{
  __shared__ __align__(16) ushort_t sAh[4][16*PK2];
  __shared__ __align__(16) ushort_t sAl[4][16*PK2];
  int tid = threadIdx.x, lane = tid & 63, wave = tid >> 6;
  int l15 = lane & 15, quad = lane >> 4;
  int base = blockIdx.x * 64 + wave * 16;
  int g = blockIdx.x >> 5;

  float mean = 0.f, rstd = 1.f, w0 = 0.f, w1 = 0.f, w2 = 0.f, bb = 0.f;
  if (MODE) {
    float a = sA[g*64 + lane], q = sB[g*64 + lane];
    mean = a * (1.f / NSAMP);
    float var = q * (1.f / NSAMP) - mean * mean;
    rstd = rsqrtf(var + EPS);
  } else {
    w0 = encW[lane]; w1 = encW[64 + lane]; w2 = encW[128 + lane];
    bb = encb[lane];
  }

  ushort_t* ah_s = sAh[wave];
  ushort_t* al_s = sAl[wave];
  #pragma unroll
  for (int r = 0; r < 16; r++) {
    int n = base + r;
    float v;
    if (MODE) v = (in[(size_t)n*64 + lane] - mean) * rstd;
    else      v = fmaf(in[n*3+2], w2, fmaf(in[n*3+1], w1, fmaf(in[n*3+0], w0, bb)));
    unsigned short hb = f2bf(v);
    ah_s[r*PK2 + lane] = hb;
    al_s[r*PK2 + lane] = f2bf(v - bf2f(hb));
  }

  s16x8 ah[2], al[2];
  #pragma unroll
  for (int kb = 0; kb < 2; kb++) {
    int idx = l15*PK2 + kb*32 + quad*8;
    ah[kb] = *(const s16x8*)&ah_s[idx];
    al[kb] = *(const s16x8*)&al_s[idx];
  }

  #pragma unroll
  for (int ct = 0; ct < 12; ct++) {
    f32x4 acc = (f32x4){0.f, 0.f, 0.f, 0.f};
    #pragma unroll
    for (int kb = 0; kb < 2; kb++) {
      int woff = (ct*16 + l15)*PK2 + kb*32 + quad*8;
      s16x8 bh = *(const s16x8*)(Wh + woff);
      s16x8 bl = *(const s16x8*)(Wl + woff);
      acc = __builtin_amdgcn_mfma_f32_16x16x32_bf16(al[kb], bl, acc, 0, 0, 0);
      acc = __builtin_amdgcn_mfma_f32_16x16x32_bf16(al[kb], bh, acc, 0, 0, 0);
      acc = __builtin_amdgcn_mfma_f32_16x16x32_bf16(ah[kb], bl, acc, 0, 0, 0);
      acc = __builtin_amdgcn_mfma_f32_16x16x32_bf16(ah[kb], bh, acc, 0, 0, 0);
    }
    int j = ct*16 + l15;
    float* dst; int jj;
    if (ct < 4)      { dst = P;  jj = j; }
    else if (ct < 8) { dst = Q;  jj = j - 64; }
    else             { dst = Rb; jj = j - 128; }
    #pragma unroll
    for (int rr = 0; rr < 4; rr++) {
      int row = base + quad*4 + rr;
      dst[(size_t)row*64 + jj] = acc[rr];
    }
  }
}

// ------------- fused edge MLP + segment-reduce (R9 body, grid 768) --------
__global__ __launch_bounds__(256, 3) void edge_fused_kernel(
    const float* __restrict__ Pbuf, const float* __restrict__ Qbuf,
    const int* __restrict__ psrc, const int* __restrict__ pdst,
    const float* __restrict__ b1,
    const ushort_t* __restrict__ W2hi, const ushort_t* __restrict__ W2lo,
    const float* __restrict__ b2,
    float* __restrict__ agg)
{
  __shared__ __align__(16) char smem[4][9216];
  __shared__ int  sSD[4][64];

  int tid = threadIdx.x;
  int lane = tid & 63, wave = tid >> 6;
  int l15 = lane & 15, quad = lane >> 4;

  ushort_t* mh = (ushort_t*)smem[wave];
  ushort_t* ml = mh + 32*PK2;
  float*    m2 = (float*)smem[wave];

  s16x8 w2h[2][4], w2l[2][4];
  #pragma unroll
  for (int kb = 0; kb < 2; kb++)
    #pragma unroll
    for (int ct = 0; ct < 4; ct++) {
      int off = (ct*16 + l15)*PK2 + kb*32 + quad*8;
      w2h[kb][ct] = *(const s16x8*)(W2hi + off);
      w2l[kb][ct] = *(const s16x8*)(W2lo + off);
    }
  float b1v = b1[lane];
  float b2v[4];
  #pragma unroll
  for (int ct = 0; ct < 4; ct++) b2v[ct] = b2[ct*16 + l15];

  for (int base = blockIdx.x * 128; base < NEDGES; base += gridDim.x * 128) {
    int e0 = base + wave * 32;

    {
      const int* tb = (lane < 32) ? psrc : pdst;
      int i = (lane < 32) ? (e0 + lane) : (e0 + lane - 32);
      sSD[wave][lane] = tb[i];
    }

    #pragma unroll
    for (int rb = 0; rb < 4; rb++) {
      float pv[8], qv[8];
      #pragma unroll
      for (int i = 0; i < 8; i++) {
        int r = rb*8 + i;
        int s = sSD[wave][r];
        int d = sSD[wave][32 + r];
        qv[i] = Qbuf[((size_t)s << 6) + lane];
        pv[i] = Pbuf[((size_t)d << 6) + lane];
      }
      #pragma unroll
      for (int i = 0; i < 8; i++) {
        int r = rb*8 + i;
        float v = fmaxf(pv[i] + qv[i] + b1v, 0.f);
        unsigned short hb = f2bf(v);
        mh[r*PK2 + lane] = hb;
        ml[r*PK2 + lane] = f2bf(v - bf2f(hb));
      }
    }

    f32x4 facc[2][4];
    #pragma unroll
    for (int rt = 0; rt < 2; rt++)
      #pragma unroll
      for (int ct = 0; ct < 4; ct++)
        facc[rt][ct] = (f32x4){0.f, 0.f, 0.f, 0.f};

    #pragma unroll
    for (int kb = 0; kb < 2; kb++) {
      s16x8 mhf[2], mlf[2];
      #pragma unroll
      for (int rt = 0; rt < 2; rt++) {
        int idx = (rt*16 + l15)*PK2 + kb*32 + quad*8;
        mhf[rt] = *(const s16x8*)&mh[idx];
        mlf[rt] = *(const s16x8*)&ml[idx];
      }
      #pragma unroll
      for (int ct = 0; ct < 4; ct++)
        #pragma unroll
        for (int rt = 0; rt < 2; rt++) {
          facc[rt][ct] = __builtin_amdgcn_mfma_f32_16x16x32_bf16(mlf[rt], w2l[kb][ct], facc[rt][ct], 0, 0, 0);
          facc[rt][ct] = __builtin_amdgcn_mfma_f32_16x16x32_bf16(mlf[rt], w2h[kb][ct], facc[rt][ct], 0, 0, 0);
          facc[rt][ct] = __builtin_amdgcn_mfma_f32_16x16x32_bf16(mhf[rt], w2l[kb][ct], facc[rt][ct], 0, 0, 0);
          facc[rt][ct] = __builtin_amdgcn_mfma_f32_16x16x32_bf16(mhf[rt], w2h[kb][ct], facc[rt][ct], 0, 0, 0);
        }
    }

    #pragma unroll
    for (int rt = 0; rt < 2; rt++)
      #pragma unroll
      for (int ct = 0; ct < 4; ct++)
        #pragma unroll
        for (int r = 0; r < 4; r++)
          m2[(rt*16 + quad*4 + r)*68 + ct*16 + l15] = fmaxf(facc[rt][ct][r] + b2v[ct], 0.f);

    int curd = sSD[wave][32];
    float acc = 0.f;
    #pragma unroll
    for (int r = 0; r < 32; r++) {
      int d = sSD[wave][32 + r];
      float v = m2[r*68 + lane];
      if (d != curd) {
        unsafeAtomicAdd(&agg[((size_t)curd << 6) + lane], acc);
        acc = 0.f; curd = d;
      }
      acc += v;
    }
    unsafeAtomicAdd(&agg[((size_t)curd << 6) + lane], acc);
  }
}

// ------------- node MLP -------------
__global__ __launch_bounds__(256) void node_mfma_kernel(
    const float* __restrict__ aggF, const float* __restrict__ Rbuf,
    const ushort_t* __restrict__ W1h, const ushort_t* __restrict__ W1l,
    const float* __restrict__ b1,
    const ushort_t* __restrict__ W2h, const ushort_t* __restrict__ W2l,
    const float* __restrict__ b2,
    float* __restrict__ uout, float* __restrict__ sA, float* __restrict__ sB)
{
  __shared__ __align__(16) ushort_t sMh[4][16*PK2];
  __shared__ __align__(16) ushort_t sMl[4][16*PK2];
  int tid = threadIdx.x, lane = tid & 63, wave = tid >> 6;
  int l15 = lane & 15, quad = lane >> 4;
  int base = blockIdx.x * 64 + wave * 16;
  int g = blockIdx.x >> 5;

  s16x8 ah[2], al[2];
  {
    int em = base + l15;
    #pragma unroll
    for (int kb = 0; kb < 2; kb++) {
      size_t off = (size_t)em*64 + kb*32 + quad*8;
      float4 v0 = *(const float4*)(aggF + off);
      float4 v1 = *(const float4*)(aggF + off + 4);
      float vv[8] = {v0.x,v0.y,v0.z,v0.w,v1.x,v1.y,v1.z,v1.w};
      s16x8 hh, ll;
      #pragma unroll
      for (int j = 0; j < 8; j++) {
        unsigned short hb = f2bf(vv[j]);
        hh[j] = (short)hb;
        ll[j] = (short)f2bf(vv[j] - bf2f(hb));
      }
      ah[kb] = hh; al[kb] = ll;
    }
  }

  ushort_t* mh = sMh[wave];
  ushort_t* ml = sMl[wave];
  float b1v[4], b2v[4];
  #pragma unroll
  for (int ct = 0; ct < 4; ct++) { b1v[ct] = b1[ct*16+l15]; b2v[ct] = b2[ct*16+l15]; }

  #pragma unroll
  for (int ct = 0; ct < 4; ct++) {
    f32x4 acc = (f32x4){0.f, 0.f, 0.f, 0.f};
    #pragma unroll
    for (int kb = 0; kb < 2; kb++) {
      int woff = (ct*16 + l15)*PK2 + kb*32 + quad*8;
      s16x8 bh = *(const s16x8*)(W1h + woff);
      s16x8 bl = *(const s16x8*)(W1l + woff);
      acc = __builtin_amdgcn_mfma_f32_16x16x32_bf16(al[kb], bl, acc, 0, 0, 0);
      acc = __builtin_amdgcn_mfma_f32_16x16x32_bf16(al[kb], bh, acc, 0, 0, 0);
      acc = __builtin_amdgcn_mfma_f32_16x16x32_bf16(ah[kb], bl, acc, 0, 0, 0);
      acc = __builtin_amdgcn_mfma_f32_16x16x32_bf16(ah[kb], bh, acc, 0, 0, 0);
    }
    int j = ct*16 + l15;
    #pragma unroll
    for (int rr = 0; rr < 4; rr++) {
      int row = quad*4 + rr;
      float v = acc[rr] + Rbuf[(size_t)(base+row)*64 + j] + b1v[ct];
      v = fmaxf(v, 0.f);
      unsigned short hb = f2bf(v);
      mh[row*PK2 + j] = hb;
      ml[row*PK2 + j] = f2bf(v - bf2f(hb));
    }
  }

  s16x8 mhf[2], mlf[2];
  #pragma unroll
  for (int kb = 0; kb < 2; kb++) {
    int idx = l15*PK2 + kb*32 + quad*8;
    mhf[kb] = *(const s16x8*)&mh[idx];
    mlf[kb] = *(const s16x8*)&ml[idx];
  }
  #pragma unroll
  for (int ct = 0; ct < 4; ct++) {
    f32x4 facc = (f32x4){0.f, 0.f, 0.f, 0.f};
    #pragma unroll
    for (int kb = 0; kb < 2; kb++) {
      int woff = (ct*16 + l15)*PK2 + kb*32 + quad*8;
      s16x8 bh = *(const s16x8*)(W2h + woff);
      s16x8 bl = *(const s16x8*)(W2l + woff);
      facc = __builtin_amdgcn_mfma_f32_16x16x32_bf16(mlf[kb], bl, facc, 0, 0, 0);
      facc = __builtin_amdgcn_mfma_f32_16x16x32_bf16(mlf[kb], bh, facc, 0, 0, 0);
      facc = __builtin_amdgcn_mfma_f32_16x16x32_bf16(mhf[kb], bl, facc, 0, 0, 0);
      facc = __builtin_amdgcn_mfma_f32_16x16x32_bf16(mhf[kb], bh, facc, 0, 0, 0);
    }
    int j = ct*16 + l15;
    float s = 0.f, s2 = 0.f;
    #pragma unroll
    for (int rr = 0; rr < 4; rr++) {
      int row = quad*4 + rr;
      float v = fmaxf(facc[rr] + b2v[ct], 0.f);
      uout[(size_t)(base+row)*64 + j] = v;
      s += v; s2 += v*v;
    }
    s  += __shfl_xor(s, 16);  s  += __shfl_xor(s, 32);
    s2 += __shfl_xor(s2, 16); s2 += __shfl_xor(s2, 32);
    if (quad == 0) {
      unsafeAtomicAdd(&sA[g*64 + j], s);
      unsafeAtomicAdd(&sB[g*64 + j], s2);
    }
  }
}

// ------------- decoder -------------
__global__ __launch_bounds__(64) void decoder_kernel(
    const float* __restrict__ u, const float* __restrict__ sA,
    const float* __restrict__ sB, const float* __restrict__ W,
    const float* __restrict__ b, float* __restrict__ X)
{
  __shared__ float sh[64][65];
  __shared__ float sm[64], sr[64];
  int lane = threadIdx.x;
  int nb = blockIdx.x * 64;
  int g = blockIdx.x >> 5;
  {
    float a = sA[g*64 + lane], q = sB[g*64 + lane];
    float mean = a * (1.f / NSAMP);
    float var = q * (1.f / NSAMP) - mean * mean;
    sm[lane] = mean;
    sr[lane] = rsqrtf(var + EPS);
  }
  for (int r = 0; r < 64; r++) sh[r][lane] = u[(size_t)(nb + r) * 64 + lane];
  __syncthreads();
  float a0 = b[0], a1 = b[1], a2 = b[2];
  #pragma unroll
  for (int c = 0; c < 64; c++) {
    float v = (sh[lane][c] - sm[c]) * sr[c];
    a0 = fmaf(v, W[c*3+0], a0);
    a1 = fmaf(v, W[c*3+1], a1);
    a2 = fmaf(v, W[c*3+2], a2);
  }
  float inv = 1.f / sqrtf(a0*a0 + a1*a1 + a2*a2);
  int n = nb + lane;
  X[n*3+0] = a0 * inv;
  X[n*3+1] = a1 * inv;
  X[n*3+2] = a2 * inv;
}

// ------------- MMD: fused kXX (blocks 0..511) + kXY (blocks 512..527) ------
__device__ inline float block_reduce_sum(float v) {
  #pragma unroll
  for (int o = 32; o > 0; o >>= 1) v += __shfl_down(v, o, 64);
  __shared__ float red[4];
  int lane = threadIdx.x & 63, w = threadIdx.x >> 6;
  if (lane == 0) red[w] = v;
  __syncthreads();
  float t = 0.f;
  if (threadIdx.x == 0) t = red[0] + red[1] + red[2] + red[3];
  return t;
}

__global__ __launch_bounds__(256) void mmd_kernel(
    const float* __restrict__ X, YArr Y,
    float* __restrict__ kxx, float* __restrict__ kxy)
{
  if (blockIdx.x < 512) {
    int b  = blockIdx.x >> 5;
    int nt = blockIdx.x & 31;
    const float* Xb = X + (size_t)b * NSAMP * 3;
    __shared__ float sx[192];
    if (threadIdx.x < 192) sx[threadIdx.x] = Xb[nt*192 + threadIdx.x];
    __syncthreads();
    float ps = 0.f;
    for (int it = 0; it < 8; it++) {
      int m = it*256 + threadIdx.x;
      float x0 = Xb[m*3+0], x1 = Xb[m*3+1], x2 = Xb[m*3+2];
      #pragma unroll
      for (int n = 0; n < 64; n++) {
        float d = x0*sx[n*3+0] + x1*sx[n*3+1] + x2*sx[n*3+2];
        ps += __expf(2.f*d - 2.f);
      }
    }
    float t = block_reduce_sum(ps);
    if (threadIdx.x == 0) atomicAdd(&kxx[b], t);
  } else {
    int b = blockIdx.x - 512;
    const float* Xb = X + (size_t)b * NSAMP * 3;
    float ps = 0.f;
    for (int it = 0; it < 8; it++) {
      int n = it*256 + threadIdx.x;
      float x0 = Xb[n*3+0], x1 = Xb[n*3+1], x2 = Xb[n*3+2];
      #pragma unroll
      for (int m = 0; m < 64; m++) {
        float d = x0*Y.v[m*3+0] + x1*Y.v[m*3+1] + x2*Y.v[m*3+2];
        ps += __expf(2.f*d - 2.f);
      }
    }
    float t = block_reduce_sum(ps);
    if (threadIdx.x == 0) kxy[b] = t;
  }
}

__global__ void loss_kernel(const float* __restrict__ kxx,
                            const float* __restrict__ kxy,
                            float kyy, float* __restrict__ out)
{
  if (threadIdx.x == 0 && blockIdx.x == 0) {
    float s = 0.f;
    for (int b = 0; b < NBATCH; b++)
      s += kxx[b] * (1.0f/((float)NSAMP*(float)NSAMP))
         - 2.0f * kxy[b] * (1.0f/((float)NSAMP*64.0f));
    out[0] = s * (1.0f/NBATCH) + kyy;
  }
}

// ------------- launch -------------
extern "C" void kernel_launch(void* const* d_in, const int* in_sizes, int n_in,
                              void* d_out, int out_size, void* d_ws, size_t ws_size,
                              hipStream_t stream)
{
  const float* x    = (const float*)d_in[0];
  const int*   esrc = (const int*)  d_in[1];
  const int*   edst = (const int*)  d_in[2];
  const float* encW = (const float*)d_in[4];
  const float* encb = (const float*)d_in[5];
  const float* m1W  = (const float*)d_in[6];
  const float* m1b  = (const float*)d_in[7];
  const float* m2W  = (const float*)d_in[8];
  const float* m2b  = (const float*)d_in[9];
  const float* u1W  = (const float*)d_in[10];
  const float* u1b  = (const float*)d_in[11];
  const float* u2W  = (const float*)d_in[12];
  const float* u2b  = (const float*)d_in[13];
  const float* decW = (const float*)d_in[14];
  const float* decb = (const float*)d_in[15];
  float* out = (float*)d_out;

  const size_t NF = (size_t)NNODES * 64;
  // single zero region: [aggAll | statsA | statsB | kxx | icnt]
  float* aggAll = (float*)d_ws;        // 4 * NF
  float* statsA = aggAll + 4*NF;       // 4096
  float* statsB = statsA + 4096;       // 4096
  float* kxx    = statsB + 4096;       // 16
  int*   icnt   = (int*)(kxx + 16);    // 32768
  size_t zero_bytes = (4*NF + 4096 + 4096 + 16) * sizeof(float) + NNODES * sizeof(int);

  float* u_buf  = (float*)(icnt + NNODES);
  float* Pbuf   = u_buf + NF;
  float* Qbuf   = Pbuf + NF;
  float* Rbuf   = Qbuf + NF;
  float* kxy    = Rbuf + NF;           // 16
  int* ioffs    = (int*)(kxy + 16);
  int* icur     = ioffs + NNODES;
  int* psrc     = icur + NNODES;
  int* pdst     = psrc + NEDGES;
  ushort_t* us  = (ushort_t*)(pdst + NEDGES);
  ushort_t* wc_hi  = us;  us += 4*192*PK2;
  ushort_t* wc_lo  = us;  us += 4*192*PK2;
  ushort_t* w1b_hi = us;  us += 4*64*PK2;
  ushort_t* w1b_lo = us;  us += 4*64*PK2;
  ushort_t* w2e_hi = us;  us += 4*64*PK2;
  ushort_t* w2e_lo = us;  us += 4*64*PK2;
  ushort_t* w2n_hi = us;  us += 4*64*PK2;
  ushort_t* w2n_lo = us;  us += 4*64*PK2;

  float* X = out + 1;

  hipMemsetAsync(aggAll, 0, zero_bytes, stream);

  setup_kernel<<<384 + NEDGES/256, 256, 0, stream>>>(
      m1W, m2W, u1W, u2W,
      wc_hi, wc_lo, w1b_hi, w1b_lo, w2e_hi, w2e_lo, w2n_hi, w2n_lo,
      edst, icnt);
  scan_kernel<<<1, 1024, 0, stream>>>(icnt, ioffs, icur);
  fill_kernel<<<NEDGES/256, 256, 0, stream>>>(esrc, edst, icur, psrc, pdst);

  for (int l = 0; l < 4; l++) {
    const ushort_t* wch = wc_hi + (size_t)l*192*PK2;
    const ushort_t* wcl = wc_lo + (size_t)l*192*PK2;
    if (l == 0)
      norm_pqr_kernel<0><<<512, 256, 0, stream>>>(
          x, nullptr, nullptr, encW, encb, wch, wcl, Pbuf, Qbuf, Rbuf);
    else
      norm_pqr_kernel<1><<<512, 256, 0, stream>>>(
          u_buf, statsA + (l-1)*1024, statsB + (l-1)*1024, nullptr, nullptr,
          wch, wcl, Pbuf, Qbuf, Rbuf);

    edge_fused_kernel<<<768, 256, 0, stream>>>(
        Pbuf, Qbuf, psrc, pdst, m1b + l*64,
        w2e_hi + (size_t)l*64*PK2, w2e_lo + (size_t)l*64*PK2, m2b + l*64,
        aggAll + (size_t)l*NF);

    node_mfma_kernel<<<512, 256, 0, stream>>>(
        aggAll + (size_t)l*NF, Rbuf,
        w1b_hi + (size_t)l*64*PK2, w1b_lo + (size_t)l*64*PK2, u1b + l*64,
        w2n_hi + (size_t)l*64*PK2, w2n_lo + (size_t)l*64*PK2, u2b + l*64,
        u_buf, statsA + l*1024, statsB + l*1024);
  }

  decoder_kernel<<<NNODES/64, 64, 0, stream>>>(
      u_buf, statsA + 3*1024, statsB + 3*1024, decW, decb, X);

  YArr Y;
  {
    const double pi = 3.14159265358979323846;
    double phi = pi * (3.0 - sqrt(5.0));
    for (int i = 0; i < 64; i++) {
      double y  = 1.0 - 2.0 * (double)i / 63.0;
      double r  = sqrt(fmax(0.0, 1.0 - y*y));
      double th = phi * (double)i;
      Y.v[i*3+0] = (float)(cos(th) * r);
      Y.v[i*3+1] = (float)y;
      Y.v[i*3+2] = (float)(sin(th) * r);
    }
  }
  double kyy_acc = 0.0;
  for (int i = 0; i < 64; i++)
    for (int j = 0; j < 64; j++) {
      double d = (double)Y.v[i*3+0]*Y.v[j*3+0]
               + (double)Y.v[i*3+1]*Y.v[j*3+1]
               + (double)Y.v[i*3+2]*Y.v[j*3+2];
      kyy_acc += exp(2.0*d - 2.0);
    }
  float kyy = (float)(kyy_acc / 4096.0);

  mmd_kernel<<<528, 256, 0, stream>>>(X, Y, kxx, kxy);
  loss_kernel<<<1, 64, 0, stream>>>(kxx, kxy, kyy, out);
}